// Round 4
// baseline (436.741 us; speedup 1.0000x reference)
//
#include <hip/hip_runtime.h>
#include <stdint.h>
#include <stddef.h>

typedef __attribute__((ext_vector_type(8))) short short8;
typedef __attribute__((ext_vector_type(4))) float f32x4;

// ---- sizes ----
// x: (8, 64, 32, 32, 96) f32.  NH=4, hd=16, scale = 0.25
// intermediates q,k,v: bf16, per (b,o): layout [ch=d/8][pos][dl=d%8], pos = h*32+w for ALL of q,k,v
#define PER_BO 98304            // 12 * 8192 ushorts per (b,o)
#define CSTRIDE 8192            // 1024 pos * 8 dl

__device__ __forceinline__ unsigned short f2bf(float f) {
    union { float f; unsigned int u; } v; v.f = f;
    unsigned int r = (v.u + 0x7FFFu + ((v.u >> 16) & 1u)) >> 16;
    return (unsigned short)r;
}

__device__ __forceinline__ unsigned int cvtpk(float lo, float hi) {
    unsigned int r;
    asm("v_cvt_pk_bf16_f32 %0, %1, %2" : "=v"(r) : "v"(lo), "v"(hi));
    return r;
}

// ============================ Kernel 1: projection GEMM (MFMA) ============================
// C[384 pos, 192 out] per block; block = 4 full (h,w) d-columns => all output 64B lines
// fully covered by one block (write-combining in L2). A (x) loaded straight to registers
// in fragment layout, hi/lo bf16 split via v_cvt_pk_bf16_f32. W in LDS (swizzled). 1 barrier.
__global__ __launch_bounds__(512, 4) void proj_mfma(
    const float* __restrict__ x, const float* __restrict__ w_sr, const float* __restrict__ b_sr,
    const float* __restrict__ Wq, const float* __restrict__ bq,
    const float* __restrict__ Wkv, const float* __restrict__ bkv,
    unsigned short* __restrict__ qb, unsigned short* __restrict__ kb, unsigned short* __restrict__ vb)
{
    __shared__ unsigned short Wh[192 * 64];
    __shared__ float bl[192];

    int t = threadIdx.x;
    int bidx = blockIdx.x;
    int b = bidx >> 8;                 // 8 batches x 256 blocks
    int blk = bidx & 255;

    int l = t & 63;
    int wvi = t >> 6;                  // 0..7; wave owns pos-tiles wvi*3 .. wvi*3+2
    int lr = l & 15, hk = l >> 4;

    // ---- A: load x straight into registers (fragment layout), issue first ----
    const float* xb = x + (size_t)b * 6291456 + (size_t)blk * 384;
    float af[3][16];
#pragma unroll
    for (int pi = 0; pi < 3; ++pi) {
        int pt = wvi * 3 + pi;
        const float* xp = xb + (size_t)(hk * 8) * 98304 + pt * 16 + lr;
#pragma unroll
        for (int j = 0; j < 8; ++j) {
            af[pi][j]     = xp[(size_t)j * 98304];
            af[pi][8 + j] = xp[(size_t)(32 + j) * 98304];
        }
    }

    // ---- stage W_eff (bf16, swizzled): element (o,c) -> Wh[o*64 + ((c>>3)^(o&7))*8 + (c&7)] ----
#pragma unroll
    for (int i = 0; i < 6; ++i) {
        int qi = t + i * 512;          // quad index, 3072 total
        int o = qi >> 4;
        int cq = qi & 15;              // c = cq*4
        int c = cq * 4;
        float4 wv4;
        if (o < 64) wv4 = *reinterpret_cast<const float4*>(Wq + o * 64 + c);
        else {
            wv4 = *reinterpret_cast<const float4*>(Wkv + (o - 64) * 64 + c);
            float4 sr = *reinterpret_cast<const float4*>(w_sr + c);
            wv4.x *= sr.x; wv4.y *= sr.y; wv4.z *= sr.z; wv4.w *= sr.w;
        }
        uint2 pk; pk.x = cvtpk(wv4.x, wv4.y); pk.y = cvtpk(wv4.z, wv4.w);
        int sw = (cq >> 1) ^ (o & 7);
        *reinterpret_cast<uint2*>(&Wh[o * 64 + sw * 8 + (cq & 1) * 4]) = pk;
    }
    if (t < 192) {
        float s;
        if (t < 64) s = bq[t];
        else {
            s = bkv[t - 64];
            for (int c = 0; c < 64; ++c) s += Wkv[(t - 64) * 64 + c] * b_sr[c];
        }
        bl[t] = s;
    }
    __syncthreads();

    // ---- convert A to hi/lo bf16 fragments (cvt_pk) ----
    short8 ahf[3][2], alf[3][2];
#pragma unroll
    for (int pi = 0; pi < 3; ++pi) {
#pragma unroll
        for (int half = 0; half < 2; ++half) {
            union { unsigned int u[4]; short8 v; } H, L;
#pragma unroll
            for (int q = 0; q < 4; ++q) {
                float f0 = af[pi][half * 8 + 2 * q];
                float f1 = af[pi][half * 8 + 2 * q + 1];
                unsigned int hp = cvtpk(f0, f1);
                float h0 = __uint_as_float(hp << 16);
                float h1 = __uint_as_float(hp & 0xffff0000u);
                H.u[q] = hp;
                L.u[q] = cvtpk(f0 - h0, f1 - h1);
            }
            ahf[pi][half] = H.v; alf[pi][half] = L.v;
        }
    }

    // ---- per-pt store offsets (same layout for q,k,v now) ----
    size_t offs[3];
#pragma unroll
    for (int pi = 0; pi < 3; ++pi) {
        int p0 = (wvi * 3 + pi) * 16 + hk * 4;
        int hwl = p0 / 96;
        int d = p0 - hwl * 96;
        int ch = d >> 3, dlb = d & 7;
        int hw = blk * 4 + hwl;
        offs[pi] = (size_t)ch * CSTRIDE + (size_t)hw * 8 + dlb;
    }

    float biasv[12];
#pragma unroll
    for (int ot = 0; ot < 12; ++ot) biasv[ot] = bl[ot * 16 + lr];

    f32x4 zero4 = {0.f, 0.f, 0.f, 0.f};
    int s7 = lr & 7;

    // ---- main loop: ot outer (B-frags read once), pt inner (A resident) ----
#pragma unroll
    for (int ot = 0; ot < 12; ++ot) {
        int o = ot * 16 + lr;
        const unsigned short* wr = &Wh[o * 64];
        short8 b0 = *reinterpret_cast<const short8*>(wr + ((hk ^ s7) * 8));
        short8 b1 = *reinterpret_cast<const short8*>(wr + (((hk + 4) ^ s7) * 8));
        float bo = biasv[ot];
        unsigned short* basep;
        if (ot < 4)       basep = qb + (size_t)(b * 64 + o) * PER_BO;
        else if (ot < 8)  basep = kb + (size_t)(b * 64 + (o - 64)) * PER_BO;
        else              basep = vb + (size_t)(b * 64 + (o - 128)) * PER_BO;
#pragma unroll
        for (int pi = 0; pi < 3; ++pi) {
            f32x4 acc = __builtin_amdgcn_mfma_f32_16x16x32_bf16(ahf[pi][0], b0, zero4, 0, 0, 0);
            acc = __builtin_amdgcn_mfma_f32_16x16x32_bf16(ahf[pi][1], b1, acc, 0, 0, 0);
            acc = __builtin_amdgcn_mfma_f32_16x16x32_bf16(alf[pi][0], b0, acc, 0, 0, 0);
            acc = __builtin_amdgcn_mfma_f32_16x16x32_bf16(alf[pi][1], b1, acc, 0, 0, 0);
            uint2 st;
            st.x = cvtpk(acc[0] + bo, acc[1] + bo);
            st.y = cvtpk(acc[2] + bo, acc[3] + bo);
            *reinterpret_cast<uint2*>(basep + offs[pi]) = st;
        }
    }
}

// ============================ Kernel 2: attention ============================
// one block per (b, n, c) triple. 1024 threads = 16 waves = 4 (h,g)-tiles x 4 d-subgroups.
// v is now h-major in global; transpose happens in the Vs staging addressing:
// Vs[dl][j][g], row stride 36 ushorts, plane stride 1152.
__global__ __launch_bounds__(1024, 4) void attn_kernel(
    const unsigned short* __restrict__ qb, const unsigned short* __restrict__ kb,
    const unsigned short* __restrict__ vb,
    const float* __restrict__ gamma, const float* __restrict__ beta,
    float* __restrict__ out)
{
    extern __shared__ char smem[];
    unsigned short* Qs = (unsigned short*)smem;
    unsigned short* Ks = (unsigned short*)(smem + 20480);
    unsigned short* Vs = (unsigned short*)(smem + 40960);
    unsigned short* Ps = (unsigned short*)(smem + 61440);
    float* Os = (float*)(smem + 71680);
    float* lred = (float*)(smem + 40960);

    int t = threadIdx.x;
    int l = t & 63;
    int wv = t >> 6;
    int tile = wv & 3;
    int hb = tile >> 1, gb = tile & 1;
    int dsub = wv >> 2;
    int lr = l & 15, lk = l >> 4;

    int id = blockIdx.x;
    int b = id >> 6;
    int n = (id >> 4) & 3;
    int oc = id & 63;   // n*16 + c

    const unsigned short* qp = qb + (size_t)(b * 64 + oc) * PER_BO;
    const unsigned short* kp = kb + (size_t)(b * 64 + oc) * PER_BO;
    const unsigned short* vp = vb + (size_t)(b * 64 + oc) * PER_BO;

    float gm = gamma[n], bt = beta[n];
    float decv[4];
#pragma unroll
    for (int r = 0; r < 4; ++r) {
        int hh = hb * 16 + lk * 4 + r;
        int gg = gb * 16 + lr;
        float dc = 2.0f * fabsf((float)(hh - gg)) * gm + bt;
        float sp = fmaxf(dc, 0.0f) + log1pf(__expf(-fabsf(dc)));
        decv[r] = __expf(-sp);
    }

    const float scale = 0.25f;
    f32x4 zero4 = {0.f, 0.f, 0.f, 0.f};
    float lacc[4] = {0.f, 0.f, 0.f, 0.f};

    int qfoff = (hb * 16 + lr) * 40 + lk * 8;
    int kfoff = (gb * 16 + lr) * 40 + lk * 8;
    int stage_base = (t >> 5) * 40 + (t & 31);

    // ---------------- PASS 1: denominators ----------------
    for (int ch = 0; ch < 12; ++ch) {
        __syncthreads();
        {
            uint4 uq = *reinterpret_cast<const uint4*>(qp + (size_t)ch * CSTRIDE + t * 8);
            uint4 uk = *reinterpret_cast<const uint4*>(kp + (size_t)ch * CSTRIDE + t * 8);
            const unsigned short* sq = (const unsigned short*)&uq;
            const unsigned short* sk = (const unsigned short*)&uk;
#pragma unroll
            for (int i = 0; i < 8; ++i) {
                Qs[i * 1280 + stage_base] = sq[i];
                Ks[i * 1280 + stage_base] = sk[i];
            }
        }
        __syncthreads();
#pragma unroll
        for (int rr = 0; rr < 2; ++rr) {
            int dl = dsub * 2 + rr;
            short8 a  = *reinterpret_cast<const short8*>(&Qs[dl * 1280 + qfoff]);
            short8 bf = *reinterpret_cast<const short8*>(&Ks[dl * 1280 + kfoff]);
            f32x4 s = __builtin_amdgcn_mfma_f32_16x16x32_bf16(a, bf, zero4, 0, 0, 0);
#pragma unroll
            for (int r = 0; r < 4; ++r)
                lacc[r] += __expf(s[r] * scale + decv[r]);
        }
    }
    __syncthreads();
#pragma unroll
    for (int r = 0; r < 4; ++r)
        lred[dsub * 1056 + (hb * 16 + lk * 4 + r) * 33 + gb * 16 + lr] = lacc[r];
    __syncthreads();
    float rl[4];
#pragma unroll
    for (int r = 0; r < 4; ++r) {
        int idx = (hb * 16 + lk * 4 + r) * 33 + gb * 16 + lr;
        float sum = lred[idx] + lred[1056 + idx] + lred[2112 + idx] + lred[3168 + idx];
        rl[r] = 1.0f / sum;
    }

    // ---------------- PASS 2: P and O ----------------
    int pfoff = (hb * 16 + lr) * 40 + lk * 8;
    int vfoff = (gb * 16 + lr) * 36 + lk * 8;   // Vs[dl][j][g], row stride 36

    for (int c2 = 0; c2 < 6; ++c2) {
        for (int sub = 0; sub < 2; ++sub) {
            int ch = c2 * 2 + sub;
            __syncthreads();
            {
                uint4 uq = *reinterpret_cast<const uint4*>(qp + (size_t)ch * CSTRIDE + t * 8);
                uint4 uk = *reinterpret_cast<const uint4*>(kp + (size_t)ch * CSTRIDE + t * 8);
                uint4 uv = *reinterpret_cast<const uint4*>(vp + (size_t)ch * CSTRIDE + t * 8);
                const unsigned short* sq = (const unsigned short*)&uq;
                const unsigned short* sk = (const unsigned short*)&uk;
                const unsigned short* sv = (const unsigned short*)&uv;
                int vtr = (t & 31) * 36 + (t >> 5);   // transpose: row j = w, col g = h
#pragma unroll
                for (int i = 0; i < 8; ++i) {
                    Qs[i * 1280 + stage_base] = sq[i];
                    Ks[i * 1280 + stage_base] = sk[i];
                    Vs[i * 1152 + vtr] = sv[i];
                }
            }
            __syncthreads();
            for (int rr = 0; rr < 2; ++rr) {
                int dl = dsub * 2 + rr;
                short8 a  = *reinterpret_cast<const short8*>(&Qs[dl * 1280 + qfoff]);
                short8 bf = *reinterpret_cast<const short8*>(&Ks[dl * 1280 + kfoff]);
                f32x4 s = __builtin_amdgcn_mfma_f32_16x16x32_bf16(a, bf, zero4, 0, 0, 0);
#pragma unroll
                for (int r = 0; r < 4; ++r) {
                    float pv = __expf(s[r] * scale + decv[r]) * rl[r];
                    Ps[dsub * 1280 + (hb * 16 + lk * 4 + r) * 40 + gb * 16 + lr] = f2bf(pv);
                }
                __syncthreads();
                short8 pa  = *reinterpret_cast<const short8*>(&Ps[dsub * 1280 + pfoff]);
                short8 vbf = *reinterpret_cast<const short8*>(&Vs[dl * 1152 + vfoff]);
                f32x4 o4 = __builtin_amdgcn_mfma_f32_16x16x32_bf16(pa, vbf, zero4, 0, 0, 0);
#pragma unroll
                for (int r = 0; r < 4; ++r)
                    Os[(sub * 8 + dl) * 1056 + (hb * 16 + lk * 4 + r) * 33 + gb * 16 + lr] = o4[r];
                __syncthreads();
            }
        }
        {
            size_t obase = ((size_t)(b * 64 + oc) * 1024 + t) * 96 + c2 * 16;
            int lidx = t + (t >> 5);
#pragma unroll
            for (int q2 = 0; q2 < 4; ++q2) {
                float4 ov;
                ov.x = Os[(q2 * 4 + 0) * 1056 + lidx];
                ov.y = Os[(q2 * 4 + 1) * 1056 + lidx];
                ov.z = Os[(q2 * 4 + 2) * 1056 + lidx];
                ov.w = Os[(q2 * 4 + 3) * 1056 + lidx];
                *reinterpret_cast<float4*>(out + obase + q2 * 4) = ov;
            }
        }
    }
}

extern "C" void kernel_launch(void* const* d_in, const int* in_sizes, int n_in,
                              void* d_out, int out_size, void* d_ws, size_t ws_size,
                              hipStream_t stream) {
    const float* x     = (const float*)d_in[0];
    const float* w_sr  = (const float*)d_in[1];
    const float* b_sr  = (const float*)d_in[2];
    const float* Wq    = (const float*)d_in[3];
    const float* bq    = (const float*)d_in[4];
    const float* Wkv   = (const float*)d_in[5];
    const float* bkv   = (const float*)d_in[6];
    const float* gamma = (const float*)d_in[7];
    const float* beta  = (const float*)d_in[8];
    float* out = (float*)d_out;

    unsigned short* qb = (unsigned short*)d_ws;
    unsigned short* kb = qb + (size_t)50331648;
    unsigned short* vb = kb + (size_t)50331648;

    proj_mfma<<<2048, 512, 0, stream>>>(x, w_sr, b_sr, Wq, bq, Wkv, bkv, qb, kb, vb);

    (void)hipFuncSetAttribute(reinterpret_cast<const void*>(attn_kernel),
                              hipFuncAttributeMaxDynamicSharedMemorySize, 139264);
    attn_kernel<<<512, 1024, 139264, stream>>>(qb, kb, vb, gamma, beta, out);
}